// Round 8
// baseline (744.308 us; speedup 1.0000x reference)
//
#include <hip/hip_runtime.h>

#define N_NODES 100000
#define EMB 128
#define NE 800000            // edges per edge set (pos / neg)
#define NEDGES (2 * NE)      // total edges
#define SCAN_ELEMS 1024
#define SCAN_BLOCKS ((N_NODES + SCAN_ELEMS - 1) / SCAN_ELEMS)   // 98

// windowed counting sort for CSR fill
#define NWIN 128
#define WNODES 782           // 128*782 = 100096 >= N_NODES
#define ACHUNK 8192
#define ABLOCKS ((NEDGES + ACHUNK - 1) / ACHUNK)                // 196
#define SEGCAP 14000         // per-window record capacity (mean 12512, +13 sigma)

// feature chunking: 8 chunks x 16 dims; chunk c lives on XCD c (blockIdx%8)
#define NCHUNK 8
#define CDIM 16              // dims per chunk
#define CU32 8               // u32 per node per chunk (16 bf16)

// ---------------- utility ----------------

__global__ void zero_i32_kernel(int* __restrict__ p, int n) {
    int i = blockIdx.x * blockDim.x + threadIdx.x;
    if (i < n) p[i] = 0;
}

__device__ __forceinline__ unsigned short f2bf(float f) {
    unsigned u = __builtin_bit_cast(unsigned, f);
    u += 0x7FFFu + ((u >> 16) & 1u);          // round-to-nearest-even
    return (unsigned short)(u >> 16);
}

__device__ __forceinline__ float bflo(unsigned u) { return __builtin_bit_cast(float, u << 16); }
__device__ __forceinline__ float bfhi(unsigned u) { return __builtin_bit_cast(float, u & 0xFFFF0000u); }

// ---------------- CSR build: degree count ----------------

__global__ void count_kernel(const int* __restrict__ pos_dst,
                             const int* __restrict__ neg_dst,
                             int* __restrict__ cnt) {
    int i = blockIdx.x * blockDim.x + threadIdx.x;
    if (i < NEDGES) {
        int d = (i < NE) ? pos_dst[i] : neg_dst[i - NE];
        atomicAdd(&cnt[d], 1);
    }
}

// block-level exclusive scan, 1024 elems / block (256 thr x 4)
__global__ __launch_bounds__(256) void scan1_kernel(const int* __restrict__ cnt,
                                                    int* __restrict__ rowtmp,
                                                    int* __restrict__ partials) {
    __shared__ int sums[256];
    const int tid  = threadIdx.x;
    const int idx  = blockIdx.x * SCAN_ELEMS + tid * 4;

    int v[4];
    int tsum = 0;
#pragma unroll
    for (int j = 0; j < 4; ++j) {
        int id = idx + j;
        v[j] = (id < N_NODES) ? cnt[id] : 0;
        tsum += v[j];
    }
    sums[tid] = tsum;
    __syncthreads();

    int val = tsum;
    for (int off = 1; off < 256; off <<= 1) {
        int t = (tid >= off) ? sums[tid - off] : 0;
        __syncthreads();
        val += t;
        sums[tid] = val;
        __syncthreads();
    }

    int p = val - tsum;
#pragma unroll
    for (int j = 0; j < 4; ++j) {
        int id = idx + j;
        if (id < N_NODES) rowtmp[id] = p;
        p += v[j];
    }
    if (tid == 255) partials[blockIdx.x] = val;
}

__global__ void scan2_kernel(const int* __restrict__ partials, int* __restrict__ offs) {
    if (threadIdx.x == 0 && blockIdx.x == 0) {
        int run = 0;
        for (int i = 0; i < SCAN_BLOCKS; ++i) { offs[i] = run; run += partials[i]; }
    }
}

__global__ __launch_bounds__(256) void scan3_kernel(const int* __restrict__ rowtmp,
                                                    const int* __restrict__ offs,
                                                    const int* __restrict__ cnt,
                                                    int* __restrict__ rowptr,
                                                    float* __restrict__ dinv) {
    const int off = offs[blockIdx.x];
#pragma unroll
    for (int j = 0; j < 4; ++j) {
        int id = blockIdx.x * SCAN_ELEMS + threadIdx.x + j * 256;
        if (id < N_NODES) {
            rowptr[id] = rowtmp[id] + off;
            dinv[id]   = rsqrtf((float)cnt[id] + 1.0f);  // +1 self-loop
        }
    }
    if (blockIdx.x == 0 && threadIdx.x == 0) rowptr[N_NODES] = NEDGES;
}

__global__ void binit_kernel(const int* __restrict__ rowptr, int* __restrict__ bucket_cursor) {
    int w = threadIdx.x;
    if (w < NWIN) {
        int lo = w * WNODES;
        bucket_cursor[w] = rowptr[(lo < N_NODES) ? lo : N_NODES];
    }
}

// ---- Phase A: bin edges by dst-window, append contiguously per window ----
// temp record: (d - lo) << 17 | src

__global__ __launch_bounds__(256) void binA_kernel(const int* __restrict__ pos,
                                                   const int* __restrict__ neg,
                                                   int* __restrict__ bucket_cursor,
                                                   unsigned* __restrict__ pairs) {
    __shared__ int lcnt[NWIN];
    __shared__ int lofs[NWIN];
    __shared__ int lcur[NWIN];
    __shared__ int gbase[NWIN];
    __shared__ unsigned pbuf[ACHUNK];
    __shared__ unsigned char wbuf[ACHUNK];

    const int tid  = threadIdx.x;
    const int e0   = blockIdx.x * ACHUNK;
    const int ecnt = (NEDGES - e0 < ACHUNK) ? (NEDGES - e0) : ACHUNK;

    if (tid < NWIN) lcnt[tid] = 0;
    __syncthreads();

    for (int k = tid; k < ecnt; k += 256) {
        int i = e0 + k;
        int d = (i < NE) ? pos[NE + i] : neg[i];
        atomicAdd(&lcnt[d / WNODES], 1);
    }
    __syncthreads();

    if (tid == 0) {
        int run = 0;
        for (int w = 0; w < NWIN; ++w) { lofs[w] = run; run += lcnt[w]; }
    }
    __syncthreads();
    if (tid < NWIN) {
        lcur[tid]  = lofs[tid];
        gbase[tid] = atomicAdd(&bucket_cursor[tid], lcnt[tid]);
    }
    __syncthreads();

    for (int k = tid; k < ecnt; k += 256) {
        int i = e0 + k;
        int s, d;
        if (i < NE) { s = pos[i];      d = pos[NE + i]; }
        else        { s = neg[i - NE]; d = neg[i]; }
        int w = d / WNODES;
        unsigned v = ((unsigned)(d - w * WNODES) << 17) | (unsigned)s;
        int lp = atomicAdd(&lcur[w], 1);
        pbuf[lp] = v;
        wbuf[lp] = (unsigned char)w;
    }
    __syncthreads();

    for (int k = tid; k < ecnt; k += 256) {
        int w = wbuf[k];
        pairs[gbase[w] + (k - lofs[w])] = pbuf[k];
    }
}

// ---- Phase B: per-window sort to final CSR order + fuse norm into record ----
// final record: bf16(norm)<<17 | src

__global__ __launch_bounds__(1024) void binB_kernel(const int* __restrict__ rowptr,
                                                    const float* __restrict__ dinv,
                                                    unsigned* __restrict__ pairs) {
    __shared__ unsigned colseg[SEGCAP];   // 56 KB
    __shared__ int lcur[WNODES];          // 3.1 KB
    __shared__ float dinvw[WNODES];       // 3.1 KB

    const int w    = blockIdx.x;
    const int lo   = w * WNODES;
    const int hi   = (lo + WNODES < N_NODES) ? lo + WNODES : N_NODES;
    const int nn   = hi - lo;
    const int base = rowptr[lo];
    const int cntw = rowptr[hi] - base;
    const int tid  = threadIdx.x;

    for (int k = tid; k < nn; k += 1024) {
        lcur[k]  = rowptr[lo + k] - base;
        dinvw[k] = dinv[lo + k];
    }
    __syncthreads();

    for (int k = tid; k < cntw; k += 1024) {
        unsigned v = pairs[base + k];
        int dl = v >> 17;
        int s  = (int)(v & 0x1FFFFu);
        float nrm = dinv[s] * dinvw[dl];
        unsigned u = __builtin_bit_cast(unsigned, nrm);
        unsigned nb = (u + 0x7FFFu + ((u >> 16) & 1u)) >> 16;   // RNE bf16, sign=0
        int lp = atomicAdd(&lcur[dl], 1);
        if (lp < SEGCAP) colseg[lp] = (nb << 17) | (unsigned)s;
    }
    __syncthreads();

    for (int k = tid; k < cntw; k += 1024) pairs[base + k] = colseg[k];
}

// ---------------- GEMM: Hb(bf16, chunk-major [8][N][16]) = X @ W ----------------

#define TR 64

__global__ __launch_bounds__(256) void gemm_kernel(const float* __restrict__ X,
                                                   const float* __restrict__ W,
                                                   unsigned short* __restrict__ Hb) {
    __shared__ float Xr[TR][EMB + 4];    // 33.8 KiB

    const int tid  = threadIdx.x;
    const int row0 = blockIdx.x * TR;

    for (int i = tid; i < TR * (EMB / 4); i += 256) {
        int r  = i >> 5;
        int k4 = (i & 31) << 2;
        int rr = row0 + r;
        if (rr >= N_NODES) rr = N_NODES - 1;
        *(float4*)&Xr[r][k4] = *(const float4*)&X[(size_t)rr * EMB + k4];
    }
    __syncthreads();

    const int c0 = (tid & 31) * 4;   // output col group
    const int r0 = (tid >> 5) * 8;   // 8 rows per thread

    float acc[8][4];
#pragma unroll
    for (int i = 0; i < 8; ++i)
#pragma unroll
        for (int j = 0; j < 4; ++j) acc[i][j] = 0.0f;

#pragma unroll 4
    for (int k4 = 0; k4 < EMB; k4 += 4) {
        float4 w0 = *(const float4*)&W[(size_t)(k4 + 0) * EMB + c0];
        float4 w1 = *(const float4*)&W[(size_t)(k4 + 1) * EMB + c0];
        float4 w2 = *(const float4*)&W[(size_t)(k4 + 2) * EMB + c0];
        float4 w3 = *(const float4*)&W[(size_t)(k4 + 3) * EMB + c0];
#pragma unroll
        for (int i = 0; i < 8; ++i) {
            float4 xa = *(float4*)&Xr[r0 + i][k4];
            acc[i][0] += xa.x * w0.x + xa.y * w1.x + xa.z * w2.x + xa.w * w3.x;
            acc[i][1] += xa.x * w0.y + xa.y * w1.y + xa.z * w2.y + xa.w * w3.y;
            acc[i][2] += xa.x * w0.z + xa.y * w1.z + xa.z * w2.z + xa.w * w3.z;
            acc[i][3] += xa.x * w0.w + xa.y * w1.w + xa.z * w2.w + xa.w * w3.w;
        }
    }

    const int chunk = c0 >> 4;          // 4-dim group lies within one 16-dim chunk
    const int coff  = c0 & 15;
#pragma unroll
    for (int i = 0; i < 8; ++i) {
        int rr = row0 + r0 + i;
        if (rr < N_NODES) {
            ushort4 v;
            v.x = f2bf(acc[i][0]);
            v.y = f2bf(acc[i][1]);
            v.z = f2bf(acc[i][2]);
            v.w = f2bf(acc[i][3]);
            *(ushort4*)&Hb[(size_t)chunk * N_NODES * CDIM + (size_t)rr * CDIM + coff] = v;
        }
    }
}

// ---------------- fused aggregate v3 (XCD-chunked) ----------------
// block = 4 waves x 2 nodes, one 16-dim chunk (chunk = blockIdx % 8 -> XCD).
// lane = (sub, dl): sub=lane>>2 covers 16 edges/iter; dl=lane&3 covers 4 dims (uint2).
// Reduce across sub with shfl_xor 4/8/16/32; lanes 0..3 write out.

__global__ __launch_bounds__(256) void aggregate_kernel(const int* __restrict__ rowptr,
                                                        const unsigned* __restrict__ rec,
                                                        const unsigned* __restrict__ HC,
                                                        const float* __restrict__ dinv,
                                                        const float* __restrict__ bias,
                                                        float* __restrict__ out) {
    const int chunk = blockIdx.x & 7;
    const int group = blockIdx.x >> 3;
    const int wave  = threadIdx.x >> 6;
    const int lane  = threadIdx.x & 63;
    const int sub   = lane >> 2;
    const int dl    = lane & 3;

    const unsigned* __restrict__ HCc = HC + (size_t)chunk * (N_NODES * CU32);

#pragma unroll
    for (int ni = 0; ni < 2; ++ni) {
        const int node = group * 8 + wave * 2 + ni;
        if (node >= N_NODES) break;   // wave-uniform

        const int start = rowptr[node];
        const int end   = rowptr[node + 1];

        float a0 = 0.f, a1 = 0.f, a2 = 0.f, a3 = 0.f;

        for (int e0 = start; e0 < end; e0 += 16) {
            int eidx   = e0 + sub;
            bool valid = eidx < end;
            int ei     = valid ? eidx : start;
            unsigned r = __builtin_nontemporal_load(&rec[ei]);
            int src    = (int)(r & 0x1FFFFu);
            float nrm  = valid ? __builtin_bit_cast(float, (r >> 17) << 16) : 0.0f;
            uint2 q = *(const uint2*)&HCc[(size_t)src * CU32 + dl * 2];
            a0 += nrm * bflo(q.x);
            a1 += nrm * bfhi(q.x);
            a2 += nrm * bflo(q.y);
            a3 += nrm * bfhi(q.y);
        }

#pragma unroll
        for (int off = 4; off <= 32; off <<= 1) {
            a0 += __shfl_xor(a0, off, 64);
            a1 += __shfl_xor(a1, off, 64);
            a2 += __shfl_xor(a2, off, 64);
            a3 += __shfl_xor(a3, off, 64);
        }

        if (sub == 0) {
            const float dd = dinv[node];
            const float s2 = dd * dd;
            uint2 q = *(const uint2*)&HCc[(size_t)node * CU32 + dl * 2];
            a0 += s2 * bflo(q.x);
            a1 += s2 * bfhi(q.x);
            a2 += s2 * bflo(q.y);
            a3 += s2 * bfhi(q.y);
            float4 bv = *(const float4*)&bias[chunk * CDIM + dl * 4];
            float4 o  = make_float4(a0 + bv.x, a1 + bv.y, a2 + bv.z, a3 + bv.w);
            *(float4*)&out[(size_t)node * EMB + chunk * CDIM + dl * 4] = o;
        }
    }
}

// ---------------- launch ----------------

extern "C" void kernel_launch(void* const* d_in, const int* in_sizes, int n_in,
                              void* d_out, int out_size, void* d_ws, size_t ws_size,
                              hipStream_t stream) {
    const float* x  = (const float*)d_in[0];
    const float* W0 = (const float*)d_in[1];
    const float* b0 = (const float*)d_in[2];
    const float* W1 = (const float*)d_in[3];
    const float* b1 = (const float*)d_in[4];
    const int*   pos = (const int*)d_in[5];
    const int*   neg = (const int*)d_in[6];
    float* out = (float*)d_out;

    // workspace layout (4-byte units)
    float* ws      = (float*)d_ws;
    float* dinv    = ws;                            // 100000
    unsigned short* hb = (unsigned short*)(ws + 100352);  // chunk-major [8][N][16] bf16
    int*   cnt     = (int*)(ws + 6500352);          // 100000
    int*   rowtmp  = (int*)(ws + 6600352);          // 100000
    int*   rowptr  = (int*)(ws + 6700704);          // 100001
    int*   partials= (int*)(ws + 6800708);          // 98
    int*   offs    = (int*)(ws + 6800808);          // 98
    int*   bcur    = (int*)(ws + 6800908);          // 128
    int*   colidx  = (int*)(ws + 6801100);          // 1.6M records

    const int* pos_dst = pos + NE;
    const int* neg_dst = neg + NE;

    const int agg_grid = ((N_NODES + 7) / 8) * NCHUNK;   // 12500 * 8

    // ---- CSR build (shared by both layers) ----
    zero_i32_kernel<<<(N_NODES + 255) / 256, 256, 0, stream>>>(cnt, N_NODES);
    count_kernel<<<(NEDGES + 255) / 256, 256, 0, stream>>>(pos_dst, neg_dst, cnt);
    scan1_kernel<<<SCAN_BLOCKS, 256, 0, stream>>>(cnt, rowtmp, partials);
    scan2_kernel<<<1, 64, 0, stream>>>(partials, offs);
    scan3_kernel<<<SCAN_BLOCKS, 256, 0, stream>>>(rowtmp, offs, cnt, rowptr, dinv);
    binit_kernel<<<1, NWIN, 0, stream>>>(rowptr, bcur);
    binA_kernel<<<ABLOCKS, 256, 0, stream>>>(pos, neg, bcur, (unsigned*)colidx);
    binB_kernel<<<NWIN, 1024, 0, stream>>>(rowptr, dinv, (unsigned*)colidx);

    // ---- layer 0 ----
    gemm_kernel<<<(N_NODES + TR - 1) / TR, 256, 0, stream>>>(x, W0, hb);
    aggregate_kernel<<<agg_grid, 256, 0, stream>>>(
        rowptr, (const unsigned*)colidx, (const unsigned*)hb, dinv, b0, out);

    // ---- layer 1 ----
    gemm_kernel<<<(N_NODES + TR - 1) / TR, 256, 0, stream>>>(out, W1, hb);
    aggregate_kernel<<<agg_grid, 256, 0, stream>>>(
        rowptr, (const unsigned*)colidx, (const unsigned*)hb, dinv, b1, out);
}

// Round 9
// 360.193 us; speedup vs baseline: 2.0664x; 2.0664x over previous
//
#include <hip/hip_runtime.h>

#define N_NODES 100000
#define EMB 128
#define NE 800000            // edges per edge set (pos / neg)
#define NEDGES (2 * NE)      // total edges
#define SCAN_ELEMS 1024
#define SCAN_BLOCKS ((N_NODES + SCAN_ELEMS - 1) / SCAN_ELEMS)   // 98

// windowed counting sort for CSR fill
#define NWIN 256
#define WNODES 391           // 256*391 = 100096 >= N_NODES
#define ACHUNK 8192
#define ABLOCKS ((NEDGES + ACHUNK - 1) / ACHUNK)                // 196
#define SEGCAP 7000          // per-window record capacity (mean 6256, +9 sigma)

// ---------------- utility ----------------

__global__ void zero_i32_kernel(int* __restrict__ p, int n) {
    int i = blockIdx.x * blockDim.x + threadIdx.x;
    if (i < n) p[i] = 0;
}

__device__ __forceinline__ unsigned short f2bf(float f) {
    unsigned u = __builtin_bit_cast(unsigned, f);
    u += 0x7FFFu + ((u >> 16) & 1u);          // round-to-nearest-even
    return (unsigned short)(u >> 16);
}

__device__ __forceinline__ float bflo(unsigned u) { return __builtin_bit_cast(float, u << 16); }
__device__ __forceinline__ float bfhi(unsigned u) { return __builtin_bit_cast(float, u & 0xFFFF0000u); }

// ---------------- CSR build: degree count ----------------

__global__ void count_kernel(const int* __restrict__ pos_dst,
                             const int* __restrict__ neg_dst,
                             int* __restrict__ cnt) {
    int i = blockIdx.x * blockDim.x + threadIdx.x;
    if (i < NEDGES) {
        int d = (i < NE) ? pos_dst[i] : neg_dst[i - NE];
        atomicAdd(&cnt[d], 1);
    }
}

// block-level exclusive scan, 1024 elems / block (256 thr x 4)
__global__ __launch_bounds__(256) void scan1_kernel(const int* __restrict__ cnt,
                                                    int* __restrict__ rowtmp,
                                                    int* __restrict__ partials) {
    __shared__ int sums[256];
    const int tid  = threadIdx.x;
    const int idx  = blockIdx.x * SCAN_ELEMS + tid * 4;

    int v[4];
    int tsum = 0;
#pragma unroll
    for (int j = 0; j < 4; ++j) {
        int id = idx + j;
        v[j] = (id < N_NODES) ? cnt[id] : 0;
        tsum += v[j];
    }
    sums[tid] = tsum;
    __syncthreads();

    int val = tsum;
    for (int off = 1; off < 256; off <<= 1) {
        int t = (tid >= off) ? sums[tid - off] : 0;
        __syncthreads();
        val += t;
        sums[tid] = val;
        __syncthreads();
    }

    int p = val - tsum;
#pragma unroll
    for (int j = 0; j < 4; ++j) {
        int id = idx + j;
        if (id < N_NODES) rowtmp[id] = p;
        p += v[j];
    }
    if (tid == 255) partials[blockIdx.x] = val;
}

__global__ void scan2_kernel(const int* __restrict__ partials, int* __restrict__ offs) {
    if (threadIdx.x == 0 && blockIdx.x == 0) {
        int run = 0;
        for (int i = 0; i < SCAN_BLOCKS; ++i) { offs[i] = run; run += partials[i]; }
    }
}

__global__ __launch_bounds__(256) void scan3_kernel(const int* __restrict__ rowtmp,
                                                    const int* __restrict__ offs,
                                                    const int* __restrict__ cnt,
                                                    int* __restrict__ rowptr,
                                                    float* __restrict__ dinv) {
    const int off = offs[blockIdx.x];
#pragma unroll
    for (int j = 0; j < 4; ++j) {
        int id = blockIdx.x * SCAN_ELEMS + threadIdx.x + j * 256;
        if (id < N_NODES) {
            rowptr[id] = rowtmp[id] + off;
            dinv[id]   = rsqrtf((float)cnt[id] + 1.0f);  // +1 self-loop
        }
    }
    if (blockIdx.x == 0 && threadIdx.x == 0) rowptr[N_NODES] = NEDGES;
}

__global__ void binit_kernel(const int* __restrict__ rowptr, int* __restrict__ bucket_cursor) {
    int w = threadIdx.x;
    if (w < NWIN) {
        int lo = w * WNODES;
        bucket_cursor[w] = rowptr[(lo < N_NODES) ? lo : N_NODES];
    }
}

// ---- Phase A: bin edges by dst-window, append contiguously per window ----
// temp record: (d - lo) << 17 | src

__global__ __launch_bounds__(256) void binA_kernel(const int* __restrict__ pos,
                                                   const int* __restrict__ neg,
                                                   int* __restrict__ bucket_cursor,
                                                   unsigned* __restrict__ pairs) {
    __shared__ int lcnt[NWIN];
    __shared__ int lofs[NWIN];
    __shared__ int lcur[NWIN];
    __shared__ int gbase[NWIN];
    __shared__ int stmp[NWIN];
    __shared__ unsigned pbuf[ACHUNK];
    __shared__ unsigned char wbuf[ACHUNK];

    const int tid  = threadIdx.x;
    const int e0   = blockIdx.x * ACHUNK;
    const int ecnt = (NEDGES - e0 < ACHUNK) ? (NEDGES - e0) : ACHUNK;

    if (tid < NWIN) lcnt[tid] = 0;
    __syncthreads();

    for (int k = tid; k < ecnt; k += 256) {
        int i = e0 + k;
        int d = (i < NE) ? pos[NE + i] : neg[i];
        atomicAdd(&lcnt[d / WNODES], 1);
    }
    __syncthreads();

    // parallel Hillis-Steele inclusive scan of lcnt -> stmp
    if (tid < NWIN) stmp[tid] = lcnt[tid];
    __syncthreads();
    for (int off = 1; off < NWIN; off <<= 1) {
        int v = (tid < NWIN && tid >= off) ? stmp[tid - off] : 0;
        __syncthreads();
        if (tid < NWIN) stmp[tid] += v;
        __syncthreads();
    }
    if (tid < NWIN) {
        lofs[tid]  = stmp[tid] - lcnt[tid];   // exclusive
        lcur[tid]  = stmp[tid] - lcnt[tid];
        gbase[tid] = atomicAdd(&bucket_cursor[tid], lcnt[tid]);
    }
    __syncthreads();

    for (int k = tid; k < ecnt; k += 256) {
        int i = e0 + k;
        int s, d;
        if (i < NE) { s = pos[i];      d = pos[NE + i]; }
        else        { s = neg[i - NE]; d = neg[i]; }
        int w = d / WNODES;
        unsigned v = ((unsigned)(d - w * WNODES) << 17) | (unsigned)s;
        int lp = atomicAdd(&lcur[w], 1);
        pbuf[lp] = v;
        wbuf[lp] = (unsigned char)w;
    }
    __syncthreads();

    for (int k = tid; k < ecnt; k += 256) {
        int w = wbuf[k];
        pairs[gbase[w] + (k - lofs[w])] = pbuf[k];
    }
}

// ---- Phase B: per-window sort to final CSR order + fuse norm into record ----
// final record: bf16(norm)<<17 | src

__global__ __launch_bounds__(1024) void binB_kernel(const int* __restrict__ rowptr,
                                                    const float* __restrict__ dinv,
                                                    unsigned* __restrict__ pairs) {
    __shared__ unsigned colseg[SEGCAP];   // 28 KB
    __shared__ int lcur[WNODES];
    __shared__ float dinvw[WNODES];

    const int w    = blockIdx.x;
    const int lo   = w * WNODES;
    const int hi   = (lo + WNODES < N_NODES) ? lo + WNODES : N_NODES;
    const int nn   = hi - lo;
    const int base = rowptr[lo];
    const int cntw = rowptr[hi] - base;
    const int tid  = threadIdx.x;

    for (int k = tid; k < nn; k += 1024) {
        lcur[k]  = rowptr[lo + k] - base;
        dinvw[k] = dinv[lo + k];
    }
    __syncthreads();

    for (int k = tid; k < cntw; k += 1024) {
        unsigned v = pairs[base + k];
        int dl = v >> 17;
        int s  = (int)(v & 0x1FFFFu);
        float nrm = dinv[s] * dinvw[dl];
        unsigned u = __builtin_bit_cast(unsigned, nrm);
        unsigned nb = (u + 0x7FFFu + ((u >> 16) & 1u)) >> 16;   // RNE bf16, sign=0
        int lp = atomicAdd(&lcur[dl], 1);
        if (lp < SEGCAP) colseg[lp] = (nb << 17) | (unsigned)s;
    }
    __syncthreads();

    for (int k = tid; k < cntw; k += 1024) pairs[base + k] = colseg[k];
}

// ---------------- GEMM: Hb(bf16, row-major [N][128]) = X @ W ----------------

#define TR 64

__global__ __launch_bounds__(256) void gemm_kernel(const float* __restrict__ X,
                                                   const float* __restrict__ W,
                                                   unsigned short* __restrict__ Hb) {
    __shared__ float Xr[TR][EMB + 4];    // 33.8 KiB

    const int tid  = threadIdx.x;
    const int row0 = blockIdx.x * TR;

    for (int i = tid; i < TR * (EMB / 4); i += 256) {
        int r  = i >> 5;
        int k4 = (i & 31) << 2;
        int rr = row0 + r;
        if (rr >= N_NODES) rr = N_NODES - 1;
        *(float4*)&Xr[r][k4] = *(const float4*)&X[(size_t)rr * EMB + k4];
    }
    __syncthreads();

    const int c0 = (tid & 31) * 4;   // output col group
    const int r0 = (tid >> 5) * 8;   // 8 rows per thread

    float acc[8][4];
#pragma unroll
    for (int i = 0; i < 8; ++i)
#pragma unroll
        for (int j = 0; j < 4; ++j) acc[i][j] = 0.0f;

#pragma unroll 4
    for (int k4 = 0; k4 < EMB; k4 += 4) {
        float4 w0 = *(const float4*)&W[(size_t)(k4 + 0) * EMB + c0];
        float4 w1 = *(const float4*)&W[(size_t)(k4 + 1) * EMB + c0];
        float4 w2 = *(const float4*)&W[(size_t)(k4 + 2) * EMB + c0];
        float4 w3 = *(const float4*)&W[(size_t)(k4 + 3) * EMB + c0];
#pragma unroll
        for (int i = 0; i < 8; ++i) {
            float4 xa = *(float4*)&Xr[r0 + i][k4];
            acc[i][0] += xa.x * w0.x + xa.y * w1.x + xa.z * w2.x + xa.w * w3.x;
            acc[i][1] += xa.x * w0.y + xa.y * w1.y + xa.z * w2.y + xa.w * w3.y;
            acc[i][2] += xa.x * w0.z + xa.y * w1.z + xa.z * w2.z + xa.w * w3.z;
            acc[i][3] += xa.x * w0.w + xa.y * w1.w + xa.z * w2.w + xa.w * w3.w;
        }
    }

#pragma unroll
    for (int i = 0; i < 8; ++i) {
        int rr = row0 + r0 + i;
        if (rr < N_NODES) {
            ushort4 v;
            v.x = f2bf(acc[i][0]);
            v.y = f2bf(acc[i][1]);
            v.z = f2bf(acc[i][2]);
            v.w = f2bf(acc[i][3]);
            *(ushort4*)&Hb[(size_t)rr * EMB + c0] = v;
        }
    }
}

// ---------------- fused aggregate v4 ----------------
// wave = one node. Batch-preload 64 records into lane registers (one load
// per 64 edges), distribute via shfl. 8 edges/iter in two groups of 4
// (sub = lane>>4), dl = lane&15 covers dims [dl*8, dl*8+8) via uint4.
// Two independent 256B gathers in flight per wave per iteration.

#define AGG_WAVES 4

__global__ __launch_bounds__(256) void aggregate_kernel(const int* __restrict__ rowptr,
                                                        const unsigned* __restrict__ rec,
                                                        const unsigned* __restrict__ Hb32,
                                                        const float* __restrict__ dinv,
                                                        const float* __restrict__ bias,
                                                        float* __restrict__ out) {
    const int wave = threadIdx.x >> 6;
    const int lane = threadIdx.x & 63;
    const int node = blockIdx.x * AGG_WAVES + wave;
    if (node >= N_NODES) return;

    const int sub = lane >> 4;    // 0..3
    const int dl  = lane & 15;    // 0..15

    const int start = rowptr[node];
    const int end   = rowptr[node + 1];

    float acc[8];
#pragma unroll
    for (int j = 0; j < 8; ++j) acc[j] = 0.0f;

    for (int b = start; b < end; b += 64) {
        int li = b + lane;
        unsigned rl = rec[li < end ? li : end - 1];
        int nb = end - b; if (nb > 64) nb = 64;
        for (int i = 0; i < nb; i += 8) {
            unsigned rA = __shfl(rl, i + sub, 64);
            unsigned rB = __shfl(rl, i + 4 + sub, 64);
            float nA = ((i + sub)     < nb) ? __builtin_bit_cast(float, (rA >> 17) << 16) : 0.0f;
            float nB = ((i + 4 + sub) < nb) ? __builtin_bit_cast(float, (rB >> 17) << 16) : 0.0f;
            int sA = (int)(rA & 0x1FFFFu);
            int sB = (int)(rB & 0x1FFFFu);
            uint4 qA = *(const uint4*)&Hb32[(size_t)sA * 64 + dl * 4];
            uint4 qB = *(const uint4*)&Hb32[(size_t)sB * 64 + dl * 4];
            acc[0] += nA * bflo(qA.x); acc[1] += nA * bfhi(qA.x);
            acc[2] += nA * bflo(qA.y); acc[3] += nA * bfhi(qA.y);
            acc[4] += nA * bflo(qA.z); acc[5] += nA * bfhi(qA.z);
            acc[6] += nA * bflo(qA.w); acc[7] += nA * bfhi(qA.w);
            acc[0] += nB * bflo(qB.x); acc[1] += nB * bfhi(qB.x);
            acc[2] += nB * bflo(qB.y); acc[3] += nB * bfhi(qB.y);
            acc[4] += nB * bflo(qB.z); acc[5] += nB * bfhi(qB.z);
            acc[6] += nB * bflo(qB.w); acc[7] += nB * bfhi(qB.w);
        }
    }

#pragma unroll
    for (int j = 0; j < 8; ++j) {
        acc[j] += __shfl_xor(acc[j], 16, 64);
        acc[j] += __shfl_xor(acc[j], 32, 64);
    }

    if (sub == 0) {
        const float dd = dinv[node];
        const float s2 = dd * dd;
        uint4 q = *(const uint4*)&Hb32[(size_t)node * 64 + dl * 4];
        acc[0] += s2 * bflo(q.x); acc[1] += s2 * bfhi(q.x);
        acc[2] += s2 * bflo(q.y); acc[3] += s2 * bfhi(q.y);
        acc[4] += s2 * bflo(q.z); acc[5] += s2 * bfhi(q.z);
        acc[6] += s2 * bflo(q.w); acc[7] += s2 * bfhi(q.w);

        float4 b0 = *(const float4*)&bias[dl * 8];
        float4 b1 = *(const float4*)&bias[dl * 8 + 4];
        float4 o0 = make_float4(acc[0] + b0.x, acc[1] + b0.y, acc[2] + b0.z, acc[3] + b0.w);
        float4 o1 = make_float4(acc[4] + b1.x, acc[5] + b1.y, acc[6] + b1.z, acc[7] + b1.w);
        *(float4*)&out[(size_t)node * EMB + dl * 8]     = o0;
        *(float4*)&out[(size_t)node * EMB + dl * 8 + 4] = o1;
    }
}

// ---------------- launch ----------------

extern "C" void kernel_launch(void* const* d_in, const int* in_sizes, int n_in,
                              void* d_out, int out_size, void* d_ws, size_t ws_size,
                              hipStream_t stream) {
    const float* x  = (const float*)d_in[0];
    const float* W0 = (const float*)d_in[1];
    const float* b0 = (const float*)d_in[2];
    const float* W1 = (const float*)d_in[3];
    const float* b1 = (const float*)d_in[4];
    const int*   pos = (const int*)d_in[5];
    const int*   neg = (const int*)d_in[6];
    float* out = (float*)d_out;

    // workspace layout (4-byte units)
    float* ws      = (float*)d_ws;
    float* dinv    = ws;                            // 100000
    unsigned short* hb = (unsigned short*)(ws + 100352);  // [N][128] bf16
    int*   cnt     = (int*)(ws + 6500352);          // 100000
    int*   rowtmp  = (int*)(ws + 6600352);          // 100000
    int*   rowptr  = (int*)(ws + 6700704);          // 100001
    int*   partials= (int*)(ws + 6800708);          // 98
    int*   offs    = (int*)(ws + 6800808);          // 98
    int*   bcur    = (int*)(ws + 6800908);          // 256
    int*   colidx  = (int*)(ws + 6801164);          // 1.6M records

    const int* pos_dst = pos + NE;
    const int* neg_dst = neg + NE;

    // ---- CSR build (shared by both layers) ----
    zero_i32_kernel<<<(N_NODES + 255) / 256, 256, 0, stream>>>(cnt, N_NODES);
    count_kernel<<<(NEDGES + 255) / 256, 256, 0, stream>>>(pos_dst, neg_dst, cnt);
    scan1_kernel<<<SCAN_BLOCKS, 256, 0, stream>>>(cnt, rowtmp, partials);
    scan2_kernel<<<1, 64, 0, stream>>>(partials, offs);
    scan3_kernel<<<SCAN_BLOCKS, 256, 0, stream>>>(rowtmp, offs, cnt, rowptr, dinv);
    binit_kernel<<<1, NWIN, 0, stream>>>(rowptr, bcur);
    binA_kernel<<<ABLOCKS, 256, 0, stream>>>(pos, neg, bcur, (unsigned*)colidx);
    binB_kernel<<<NWIN, 1024, 0, stream>>>(rowptr, dinv, (unsigned*)colidx);

    // ---- layer 0 ----
    gemm_kernel<<<(N_NODES + TR - 1) / TR, 256, 0, stream>>>(x, W0, hb);
    aggregate_kernel<<<(N_NODES + AGG_WAVES - 1) / AGG_WAVES, 256, 0, stream>>>(
        rowptr, (const unsigned*)colidx, (const unsigned*)hb, dinv, b0, out);

    // ---- layer 1 ----
    gemm_kernel<<<(N_NODES + TR - 1) / TR, 256, 0, stream>>>(out, W1, hb);
    aggregate_kernel<<<(N_NODES + AGG_WAVES - 1) / AGG_WAVES, 256, 0, stream>>>(
        rowptr, (const unsigned*)colidx, (const unsigned*)hb, dinv, b1, out);
}

// Round 10
// 299.797 us; speedup vs baseline: 2.4827x; 1.2015x over previous
//
#include <hip/hip_runtime.h>

#define N_NODES 100000
#define EMB 128
#define NE 800000            // edges per edge set (pos / neg)
#define NEDGES (2 * NE)      // total edges

// windowed counting sort for CSR fill
#define NWIN 256
#define WNODES 391           // 256*391 = 100096 >= N_NODES
#define WCAP 8192            // padded per-window capacity (mean 6250, max ~6600)
#define ACHUNK 8192
#define ABLOCKS ((NEDGES + ACHUNK - 1) / ACHUNK)                // 196
#define SEGCAP 7000          // per-window record capacity (mean 6256, +9 sigma)

// ---------------- utility ----------------

__device__ __forceinline__ unsigned short f2bf(float f) {
    unsigned u = __builtin_bit_cast(unsigned, f);
    u += 0x7FFFu + ((u >> 16) & 1u);          // round-to-nearest-even
    return (unsigned short)(u >> 16);
}

__device__ __forceinline__ float bflo(unsigned u) { return __builtin_bit_cast(float, u << 16); }
__device__ __forceinline__ float bfhi(unsigned u) { return __builtin_bit_cast(float, u & 0xFFFF0000u); }

__global__ void binit_kernel(int* __restrict__ bcur) {
    int w = threadIdx.x;
    if (w < NWIN) bcur[w] = w * WCAP;
}

// ---- Phase A: bin edges by dst-window into padded regions ----
// temp record: (d - w*WNODES) << 17 | src

__global__ __launch_bounds__(256) void binA_kernel(const int* __restrict__ pos,
                                                   const int* __restrict__ neg,
                                                   int* __restrict__ bucket_cursor,
                                                   unsigned* __restrict__ ptmp) {
    __shared__ int lcnt[NWIN];
    __shared__ int lofs[NWIN];
    __shared__ int lcur[NWIN];
    __shared__ int gbase[NWIN];
    __shared__ int stmp[NWIN];
    __shared__ unsigned pbuf[ACHUNK];
    __shared__ unsigned char wbuf[ACHUNK];

    const int tid  = threadIdx.x;
    const int e0   = blockIdx.x * ACHUNK;
    const int ecnt = (NEDGES - e0 < ACHUNK) ? (NEDGES - e0) : ACHUNK;

    if (tid < NWIN) lcnt[tid] = 0;
    __syncthreads();

    for (int k = tid; k < ecnt; k += 256) {
        int i = e0 + k;
        int d = (i < NE) ? pos[NE + i] : neg[i];
        atomicAdd(&lcnt[d / WNODES], 1);
    }
    __syncthreads();

    // parallel Hillis-Steele inclusive scan of lcnt
    if (tid < NWIN) stmp[tid] = lcnt[tid];
    __syncthreads();
    for (int off = 1; off < NWIN; off <<= 1) {
        int v = (tid < NWIN && tid >= off) ? stmp[tid - off] : 0;
        __syncthreads();
        if (tid < NWIN) stmp[tid] += v;
        __syncthreads();
    }
    if (tid < NWIN) {
        lofs[tid]  = stmp[tid] - lcnt[tid];   // exclusive
        lcur[tid]  = stmp[tid] - lcnt[tid];
        gbase[tid] = atomicAdd(&bucket_cursor[tid], lcnt[tid]);
    }
    __syncthreads();

    for (int k = tid; k < ecnt; k += 256) {
        int i = e0 + k;
        int s, d;
        if (i < NE) { s = pos[i];      d = pos[NE + i]; }
        else        { s = neg[i - NE]; d = neg[i]; }
        int w = d / WNODES;
        unsigned v = ((unsigned)(d - w * WNODES) << 17) | (unsigned)s;
        int lp = atomicAdd(&lcur[w], 1);
        pbuf[lp] = v;
        wbuf[lp] = (unsigned char)w;
    }
    __syncthreads();

    for (int k = tid; k < ecnt; k += 256) {
        int w = wbuf[k];
        ptmp[gbase[w] + (k - lofs[w])] = pbuf[k];
    }
}

// ---- window-base scan: wbase[w] = exclusive prefix of per-window totals ----

__global__ __launch_bounds__(NWIN) void wscan_kernel(const int* __restrict__ bcur,
                                                     int* __restrict__ wbase) {
    __shared__ int sc[NWIN];
    const int tid = threadIdx.x;
    int t = bcur[tid] - tid * WCAP;
    sc[tid] = t;
    __syncthreads();
    for (int off = 1; off < NWIN; off <<= 1) {
        int v = (tid >= off) ? sc[tid - off] : 0;
        __syncthreads();
        sc[tid] += v;
        __syncthreads();
    }
    wbase[tid] = sc[tid] - t;   // exclusive
}

// ---- Phase C: per-window LDS histogram + scan -> rowptr, dinv ----

__global__ __launch_bounds__(1024) void binC_kernel(const int* __restrict__ bcur,
                                                    const int* __restrict__ wbase,
                                                    const unsigned* __restrict__ ptmp,
                                                    int* __restrict__ rowptr,
                                                    float* __restrict__ dinv) {
    __shared__ int cnt[WNODES];
    __shared__ int sc[512];

    const int w   = blockIdx.x;
    const int lo  = w * WNODES;
    const int hi  = (lo + WNODES < N_NODES) ? lo + WNODES : N_NODES;
    const int nn  = hi - lo;
    const int tot = bcur[w] - w * WCAP;
    const int tid = threadIdx.x;
    const unsigned* __restrict__ rp = ptmp + (size_t)w * WCAP;

    for (int k = tid; k < nn; k += 1024) cnt[k] = 0;
    __syncthreads();

    for (int k = tid; k < tot; k += 1024) {
        atomicAdd(&cnt[rp[k] >> 17], 1);
    }
    __syncthreads();

    if (tid < 512) sc[tid] = (tid < nn) ? cnt[tid] : 0;
    __syncthreads();
    for (int off = 1; off < 512; off <<= 1) {
        int v = (tid < 512 && tid >= off) ? sc[tid - off] : 0;
        __syncthreads();
        if (tid < 512) sc[tid] += v;
        __syncthreads();
    }

    const int b = wbase[w];
    if (tid < nn) {
        rowptr[lo + tid] = b + sc[tid] - cnt[tid];   // exclusive
        dinv[lo + tid]   = rsqrtf((float)cnt[tid] + 1.0f);  // +1 self-loop
    }
    if (w == 0 && tid == 0) rowptr[N_NODES] = NEDGES;
}

// ---- Phase B: per-window sort to final CSR order + fuse norm into record ----
// final record: bf16(norm)<<17 | src

__global__ __launch_bounds__(1024) void binB_kernel(const int* __restrict__ bcur,
                                                    const int* __restrict__ rowptr,
                                                    const float* __restrict__ dinv,
                                                    const unsigned* __restrict__ ptmp,
                                                    unsigned* __restrict__ colidx) {
    __shared__ unsigned colseg[SEGCAP];   // 28 KB
    __shared__ int lcur[WNODES];
    __shared__ float dinvw[WNODES];

    const int w    = blockIdx.x;
    const int lo   = w * WNODES;
    const int hi   = (lo + WNODES < N_NODES) ? lo + WNODES : N_NODES;
    const int nn   = hi - lo;
    const int base = rowptr[lo];
    const int tot  = bcur[w] - w * WCAP;
    const int tid  = threadIdx.x;
    const unsigned* __restrict__ rp = ptmp + (size_t)w * WCAP;

    for (int k = tid; k < nn; k += 1024) {
        lcur[k]  = rowptr[lo + k] - base;
        dinvw[k] = dinv[lo + k];
    }
    __syncthreads();

    for (int k = tid; k < tot; k += 1024) {
        unsigned v = rp[k];
        int dl = v >> 17;
        int s  = (int)(v & 0x1FFFFu);
        float nrm = dinv[s] * dinvw[dl];
        unsigned u = __builtin_bit_cast(unsigned, nrm);
        unsigned nb = (u + 0x7FFFu + ((u >> 16) & 1u)) >> 16;   // RNE bf16, sign=0
        int lp = atomicAdd(&lcur[dl], 1);
        if (lp < SEGCAP) colseg[lp] = (nb << 17) | (unsigned)s;
    }
    __syncthreads();

    for (int k = tid; k < tot; k += 1024) colidx[base + k] = colseg[k];
}

// ---------------- GEMM: Hb(bf16 [N][128]) = X @ W  (128x128 tile, 8x8/thread) ----------------

#define GTR 128

__global__ __launch_bounds__(256) void gemm_kernel(const float* __restrict__ X,
                                                   const float* __restrict__ W,
                                                   unsigned short* __restrict__ Hb) {
    __shared__ float Xr[GTR][EMB + 4];    // 128 x 132 f = 67.6 KiB

    const int tid  = threadIdx.x;
    const int row0 = blockIdx.x * GTR;

    for (int i = tid; i < GTR * (EMB / 4); i += 256) {
        int r  = i >> 5;
        int k4 = (i & 31) << 2;
        int rr = row0 + r;
        if (rr >= N_NODES) rr = N_NODES - 1;
        *(float4*)&Xr[r][k4] = *(const float4*)&X[(size_t)rr * EMB + k4];
    }
    __syncthreads();

    const int c0 = (tid & 15) * 8;   // 8 output cols
    const int r0 = (tid >> 4) * 8;   // 8 output rows

    float acc[8][8];
#pragma unroll
    for (int i = 0; i < 8; ++i)
#pragma unroll
        for (int j = 0; j < 8; ++j) acc[i][j] = 0.0f;

    for (int k4 = 0; k4 < EMB; k4 += 4) {
        float4 wa[4], wb[4];
#pragma unroll
        for (int k = 0; k < 4; ++k) {
            wa[k] = *(const float4*)&W[(size_t)(k4 + k) * EMB + c0];
            wb[k] = *(const float4*)&W[(size_t)(k4 + k) * EMB + c0 + 4];
        }
#pragma unroll
        for (int i = 0; i < 8; ++i) {
            float4 xa = *(float4*)&Xr[r0 + i][k4];
            acc[i][0] += xa.x * wa[0].x + xa.y * wa[1].x + xa.z * wa[2].x + xa.w * wa[3].x;
            acc[i][1] += xa.x * wa[0].y + xa.y * wa[1].y + xa.z * wa[2].y + xa.w * wa[3].y;
            acc[i][2] += xa.x * wa[0].z + xa.y * wa[1].z + xa.z * wa[2].z + xa.w * wa[3].z;
            acc[i][3] += xa.x * wa[0].w + xa.y * wa[1].w + xa.z * wa[2].w + xa.w * wa[3].w;
            acc[i][4] += xa.x * wb[0].x + xa.y * wb[1].x + xa.z * wb[2].x + xa.w * wb[3].x;
            acc[i][5] += xa.x * wb[0].y + xa.y * wb[1].y + xa.z * wb[2].y + xa.w * wb[3].y;
            acc[i][6] += xa.x * wb[0].z + xa.y * wb[1].z + xa.z * wb[2].z + xa.w * wb[3].z;
            acc[i][7] += xa.x * wb[0].w + xa.y * wb[1].w + xa.z * wb[2].w + xa.w * wb[3].w;
        }
    }

#pragma unroll
    for (int i = 0; i < 8; ++i) {
        int rr = row0 + r0 + i;
        if (rr < N_NODES) {
            ushort4 v0, v1;
            v0.x = f2bf(acc[i][0]); v0.y = f2bf(acc[i][1]);
            v0.z = f2bf(acc[i][2]); v0.w = f2bf(acc[i][3]);
            v1.x = f2bf(acc[i][4]); v1.y = f2bf(acc[i][5]);
            v1.z = f2bf(acc[i][6]); v1.w = f2bf(acc[i][7]);
            *(ushort4*)&Hb[(size_t)rr * EMB + c0]     = v0;
            *(ushort4*)&Hb[(size_t)rr * EMB + c0 + 4] = v1;
        }
    }
}

// ---------------- fused aggregate (v4: batched record preload + 2x gather ILP) ----------------

#define AGG_WAVES 4

__global__ __launch_bounds__(256) void aggregate_kernel(const int* __restrict__ rowptr,
                                                        const unsigned* __restrict__ rec,
                                                        const unsigned* __restrict__ Hb32,
                                                        const float* __restrict__ dinv,
                                                        const float* __restrict__ bias,
                                                        float* __restrict__ out) {
    const int wave = threadIdx.x >> 6;
    const int lane = threadIdx.x & 63;
    const int node = blockIdx.x * AGG_WAVES + wave;
    if (node >= N_NODES) return;

    const int sub = lane >> 4;    // 0..3
    const int dl  = lane & 15;    // 0..15

    const int start = rowptr[node];
    const int end   = rowptr[node + 1];

    float acc[8];
#pragma unroll
    for (int j = 0; j < 8; ++j) acc[j] = 0.0f;

    for (int b = start; b < end; b += 64) {
        int li = b + lane;
        unsigned rl = rec[li < end ? li : end - 1];
        int nb = end - b; if (nb > 64) nb = 64;
        for (int i = 0; i < nb; i += 8) {
            unsigned rA = __shfl(rl, i + sub, 64);
            unsigned rB = __shfl(rl, i + 4 + sub, 64);
            float nA = ((i + sub)     < nb) ? __builtin_bit_cast(float, (rA >> 17) << 16) : 0.0f;
            float nB = ((i + 4 + sub) < nb) ? __builtin_bit_cast(float, (rB >> 17) << 16) : 0.0f;
            int sA = (int)(rA & 0x1FFFFu);
            int sB = (int)(rB & 0x1FFFFu);
            uint4 qA = *(const uint4*)&Hb32[(size_t)sA * 64 + dl * 4];
            uint4 qB = *(const uint4*)&Hb32[(size_t)sB * 64 + dl * 4];
            acc[0] += nA * bflo(qA.x); acc[1] += nA * bfhi(qA.x);
            acc[2] += nA * bflo(qA.y); acc[3] += nA * bfhi(qA.y);
            acc[4] += nA * bflo(qA.z); acc[5] += nA * bfhi(qA.z);
            acc[6] += nA * bflo(qA.w); acc[7] += nA * bfhi(qA.w);
            acc[0] += nB * bflo(qB.x); acc[1] += nB * bfhi(qB.x);
            acc[2] += nB * bflo(qB.y); acc[3] += nB * bfhi(qB.y);
            acc[4] += nB * bflo(qB.z); acc[5] += nB * bfhi(qB.z);
            acc[6] += nB * bflo(qB.w); acc[7] += nB * bfhi(qB.w);
        }
    }

#pragma unroll
    for (int j = 0; j < 8; ++j) {
        acc[j] += __shfl_xor(acc[j], 16, 64);
        acc[j] += __shfl_xor(acc[j], 32, 64);
    }

    if (sub == 0) {
        const float dd = dinv[node];
        const float s2 = dd * dd;
        uint4 q = *(const uint4*)&Hb32[(size_t)node * 64 + dl * 4];
        acc[0] += s2 * bflo(q.x); acc[1] += s2 * bfhi(q.x);
        acc[2] += s2 * bflo(q.y); acc[3] += s2 * bfhi(q.y);
        acc[4] += s2 * bflo(q.z); acc[5] += s2 * bfhi(q.z);
        acc[6] += s2 * bflo(q.w); acc[7] += s2 * bfhi(q.w);

        float4 b0 = *(const float4*)&bias[dl * 8];
        float4 b1 = *(const float4*)&bias[dl * 8 + 4];
        float4 o0 = make_float4(acc[0] + b0.x, acc[1] + b0.y, acc[2] + b0.z, acc[3] + b0.w);
        float4 o1 = make_float4(acc[4] + b1.x, acc[5] + b1.y, acc[6] + b1.z, acc[7] + b1.w);
        *(float4*)&out[(size_t)node * EMB + dl * 8]     = o0;
        *(float4*)&out[(size_t)node * EMB + dl * 8 + 4] = o1;
    }
}

// ---------------- launch ----------------

extern "C" void kernel_launch(void* const* d_in, const int* in_sizes, int n_in,
                              void* d_out, int out_size, void* d_ws, size_t ws_size,
                              hipStream_t stream) {
    const float* x  = (const float*)d_in[0];
    const float* W0 = (const float*)d_in[1];
    const float* b0 = (const float*)d_in[2];
    const float* W1 = (const float*)d_in[3];
    const float* b1 = (const float*)d_in[4];
    const int*   pos = (const int*)d_in[5];
    const int*   neg = (const int*)d_in[6];
    float* out = (float*)d_out;

    // workspace layout (4-byte units)
    float* ws      = (float*)d_ws;
    float* dinv    = ws;                                  // 100000
    unsigned short* hb = (unsigned short*)(ws + 100352);  // [N][128] bf16
    int*   rowptr  = (int*)(ws + 6500352);                // 100001
    int*   bcur    = (int*)(ws + 6600356);                // 256
    int*   wbase   = (int*)(ws + 6600612);                // 256
    unsigned* ptmp = (unsigned*)(ws + 6600872);           // 256*8192 = 2097152
    unsigned* colidx = (unsigned*)(ws + 8698024);         // 1.6M records

    // ---- CSR build (shared by both layers) ----
    binit_kernel<<<1, NWIN, 0, stream>>>(bcur);
    binA_kernel<<<ABLOCKS, 256, 0, stream>>>(pos, neg, bcur, ptmp);
    wscan_kernel<<<1, NWIN, 0, stream>>>(bcur, wbase);
    binC_kernel<<<NWIN, 1024, 0, stream>>>(bcur, wbase, ptmp, rowptr, dinv);
    binB_kernel<<<NWIN, 1024, 0, stream>>>(bcur, rowptr, dinv, ptmp, colidx);

    // ---- layer 0 ----
    gemm_kernel<<<(N_NODES + GTR - 1) / GTR, 256, 0, stream>>>(x, W0, hb);
    aggregate_kernel<<<(N_NODES + AGG_WAVES - 1) / AGG_WAVES, 256, 0, stream>>>(
        rowptr, colidx, (const unsigned*)hb, dinv, b0, out);

    // ---- layer 1 ----
    gemm_kernel<<<(N_NODES + GTR - 1) / GTR, 256, 0, stream>>>(out, W1, hb);
    aggregate_kernel<<<(N_NODES + AGG_WAVES - 1) / AGG_WAVES, 256, 0, stream>>>(
        rowptr, colidx, (const unsigned*)hb, dinv, b1, out);
}

// Round 11
// 280.625 us; speedup vs baseline: 2.6523x; 1.0683x over previous
//
#include <hip/hip_runtime.h>

#define N_NODES 100000
#define EMB 128
#define NE 800000            // edges per edge set (pos / neg)
#define NEDGES (2 * NE)      // total edges

// windowed counting sort for CSR fill
#define NWIN 256
#define WNODES 391           // 256*391 = 100096 >= N_NODES
#define WCAP 8192            // padded per-window capacity (mean 6250, max ~6600)
#define ACHUNK 8192
#define ABLOCKS ((NEDGES + ACHUNK - 1) / ACHUNK)                // 196
#define SEGCAP 7000          // per-window record capacity (mean 6256, +9 sigma)

// ---------------- utility ----------------

__device__ __forceinline__ unsigned short f2bf(float f) {
    unsigned u = __builtin_bit_cast(unsigned, f);
    u += 0x7FFFu + ((u >> 16) & 1u);          // round-to-nearest-even
    return (unsigned short)(u >> 16);
}

__device__ __forceinline__ float bflo(unsigned u) { return __builtin_bit_cast(float, u << 16); }
__device__ __forceinline__ float bfhi(unsigned u) { return __builtin_bit_cast(float, u & 0xFFFF0000u); }

__global__ void binit_kernel(int* __restrict__ bcur) {
    int w = threadIdx.x;
    if (w < NWIN) bcur[w] = w * WCAP;
}

// ---- Phase A: bin edges by dst-window into padded regions ----
// temp record: (d - w*WNODES) << 17 | src

__global__ __launch_bounds__(256) void binA_kernel(const int* __restrict__ pos,
                                                   const int* __restrict__ neg,
                                                   int* __restrict__ bucket_cursor,
                                                   unsigned* __restrict__ ptmp) {
    __shared__ int lcnt[NWIN];
    __shared__ int lofs[NWIN];
    __shared__ int lcur[NWIN];
    __shared__ int gbase[NWIN];
    __shared__ int stmp[NWIN];
    __shared__ unsigned pbuf[ACHUNK];
    __shared__ unsigned char wbuf[ACHUNK];

    const int tid  = threadIdx.x;
    const int e0   = blockIdx.x * ACHUNK;
    const int ecnt = (NEDGES - e0 < ACHUNK) ? (NEDGES - e0) : ACHUNK;

    if (tid < NWIN) lcnt[tid] = 0;
    __syncthreads();

    for (int k = tid; k < ecnt; k += 256) {
        int i = e0 + k;
        int d = (i < NE) ? pos[NE + i] : neg[i];
        atomicAdd(&lcnt[d / WNODES], 1);
    }
    __syncthreads();

    // parallel Hillis-Steele inclusive scan of lcnt
    if (tid < NWIN) stmp[tid] = lcnt[tid];
    __syncthreads();
    for (int off = 1; off < NWIN; off <<= 1) {
        int v = (tid < NWIN && tid >= off) ? stmp[tid - off] : 0;
        __syncthreads();
        if (tid < NWIN) stmp[tid] += v;
        __syncthreads();
    }
    if (tid < NWIN) {
        lofs[tid]  = stmp[tid] - lcnt[tid];   // exclusive
        lcur[tid]  = stmp[tid] - lcnt[tid];
        gbase[tid] = atomicAdd(&bucket_cursor[tid], lcnt[tid]);
    }
    __syncthreads();

    for (int k = tid; k < ecnt; k += 256) {
        int i = e0 + k;
        int s, d;
        if (i < NE) { s = pos[i];      d = pos[NE + i]; }
        else        { s = neg[i - NE]; d = neg[i]; }
        int w = d / WNODES;
        unsigned v = ((unsigned)(d - w * WNODES) << 17) | (unsigned)s;
        int lp = atomicAdd(&lcur[w], 1);
        pbuf[lp] = v;
        wbuf[lp] = (unsigned char)w;
    }
    __syncthreads();

    for (int k = tid; k < ecnt; k += 256) {
        int w = wbuf[k];
        ptmp[gbase[w] + (k - lofs[w])] = pbuf[k];
    }
}

// ---- window-base scan: wbase[w] = exclusive prefix of per-window totals ----

__global__ __launch_bounds__(NWIN) void wscan_kernel(const int* __restrict__ bcur,
                                                     int* __restrict__ wbase) {
    __shared__ int sc[NWIN];
    const int tid = threadIdx.x;
    int t = bcur[tid] - tid * WCAP;
    sc[tid] = t;
    __syncthreads();
    for (int off = 1; off < NWIN; off <<= 1) {
        int v = (tid >= off) ? sc[tid - off] : 0;
        __syncthreads();
        sc[tid] += v;
        __syncthreads();
    }
    wbase[tid] = sc[tid] - t;   // exclusive
}

// ---- Phase C: per-window LDS histogram + scan -> rowptr, dinv ----

__global__ __launch_bounds__(1024) void binC_kernel(const int* __restrict__ bcur,
                                                    const int* __restrict__ wbase,
                                                    const unsigned* __restrict__ ptmp,
                                                    int* __restrict__ rowptr,
                                                    float* __restrict__ dinv) {
    __shared__ int cnt[WNODES];
    __shared__ int sc[512];

    const int w   = blockIdx.x;
    const int lo  = w * WNODES;
    const int hi  = (lo + WNODES < N_NODES) ? lo + WNODES : N_NODES;
    const int nn  = hi - lo;
    const int tot = bcur[w] - w * WCAP;
    const int tid = threadIdx.x;
    const unsigned* __restrict__ rp = ptmp + (size_t)w * WCAP;

    for (int k = tid; k < nn; k += 1024) cnt[k] = 0;
    __syncthreads();

    for (int k = tid; k < tot; k += 1024) {
        atomicAdd(&cnt[rp[k] >> 17], 1);
    }
    __syncthreads();

    if (tid < 512) sc[tid] = (tid < nn) ? cnt[tid] : 0;
    __syncthreads();
    for (int off = 1; off < 512; off <<= 1) {
        int v = (tid < 512 && tid >= off) ? sc[tid - off] : 0;
        __syncthreads();
        if (tid < 512) sc[tid] += v;
        __syncthreads();
    }

    const int b = wbase[w];
    if (tid < nn) {
        rowptr[lo + tid] = b + sc[tid] - cnt[tid];   // exclusive
        dinv[lo + tid]   = rsqrtf((float)cnt[tid] + 1.0f);  // +1 self-loop
    }
    if (w == 0 && tid == 0) rowptr[N_NODES] = NEDGES;
}

// ---- Phase B: per-window sort to final CSR order + fuse norm into record ----
// final record: bf16(norm)<<17 | src

__global__ __launch_bounds__(1024) void binB_kernel(const int* __restrict__ bcur,
                                                    const int* __restrict__ rowptr,
                                                    const float* __restrict__ dinv,
                                                    const unsigned* __restrict__ ptmp,
                                                    unsigned* __restrict__ colidx) {
    __shared__ unsigned colseg[SEGCAP];   // 28 KB
    __shared__ int lcur[WNODES];
    __shared__ float dinvw[WNODES];

    const int w    = blockIdx.x;
    const int lo   = w * WNODES;
    const int hi   = (lo + WNODES < N_NODES) ? lo + WNODES : N_NODES;
    const int nn   = hi - lo;
    const int base = rowptr[lo];
    const int tot  = bcur[w] - w * WCAP;
    const int tid  = threadIdx.x;
    const unsigned* __restrict__ rp = ptmp + (size_t)w * WCAP;

    for (int k = tid; k < nn; k += 1024) {
        lcur[k]  = rowptr[lo + k] - base;
        dinvw[k] = dinv[lo + k];
    }
    __syncthreads();

    for (int k = tid; k < tot; k += 1024) {
        unsigned v = rp[k];
        int dl = v >> 17;
        int s  = (int)(v & 0x1FFFFu);
        float nrm = dinv[s] * dinvw[dl];
        unsigned u = __builtin_bit_cast(unsigned, nrm);
        unsigned nb = (u + 0x7FFFu + ((u >> 16) & 1u)) >> 16;   // RNE bf16, sign=0
        int lp = atomicAdd(&lcur[dl], 1);
        if (lp < SEGCAP) colseg[lp] = (nb << 17) | (unsigned)s;
    }
    __syncthreads();

    for (int k = tid; k < tot; k += 1024) colidx[base + k] = colseg[k];
}

// ---------------- GEMM v3: Hb(bf16 [N][128]) = X @ W ----------------
// 128x128 output tile, 8x8/thread, k-chunked (KC=32) LDS staging of BOTH
// operands: Xt transposed [32][132] + Wl [32][132] = 33.8 KB -> 4 blocks/CU.
// W read once per block from L2; X read exactly once.

#define GTR 128
#define KC  32

__global__ __launch_bounds__(256) void gemm_kernel(const float* __restrict__ X,
                                                   const float* __restrict__ W,
                                                   unsigned short* __restrict__ Hb) {
    __shared__ float Xt[KC][GTR + 4];   // [k][row], 16.9 KB
    __shared__ float Wl[KC][EMB + 4];   // [k][col], 16.9 KB

    const int tid  = threadIdx.x;
    const int row0 = blockIdx.x * GTR;

    const int c0 = (tid & 15) * 8;   // 8 output cols
    const int r0 = (tid >> 4) * 8;   // 8 output rows

    float acc[8][8];
#pragma unroll
    for (int i = 0; i < 8; ++i)
#pragma unroll
        for (int j = 0; j < 8; ++j) acc[i][j] = 0.0f;

    for (int kc = 0; kc < EMB; kc += KC) {
        // stage X chunk transposed: 128 rows x 8 float4
#pragma unroll
        for (int ii = 0; ii < 4; ++ii) {
            int i  = tid + ii * 256;
            int r  = i >> 3;
            int k4 = (i & 7) << 2;
            int rr = row0 + r;
            if (rr >= N_NODES) rr = N_NODES - 1;
            float4 v = *(const float4*)&X[(size_t)rr * EMB + kc + k4];
            Xt[k4 + 0][r] = v.x;
            Xt[k4 + 1][r] = v.y;
            Xt[k4 + 2][r] = v.z;
            Xt[k4 + 3][r] = v.w;
        }
        // stage W chunk: 32 k x 32 float4
#pragma unroll
        for (int ii = 0; ii < 4; ++ii) {
            int i  = tid + ii * 256;
            int k  = i >> 5;
            int c4 = (i & 31) << 2;
            *(float4*)&Wl[k][c4] = *(const float4*)&W[(size_t)(kc + k) * EMB + c4];
        }
        __syncthreads();

#pragma unroll 8
        for (int k = 0; k < KC; ++k) {
            float4 xa0 = *(float4*)&Xt[k][r0];
            float4 xa1 = *(float4*)&Xt[k][r0 + 4];
            float4 wa0 = *(float4*)&Wl[k][c0];
            float4 wa1 = *(float4*)&Wl[k][c0 + 4];
            float xv[8] = {xa0.x, xa0.y, xa0.z, xa0.w, xa1.x, xa1.y, xa1.z, xa1.w};
            float wv[8] = {wa0.x, wa0.y, wa0.z, wa0.w, wa1.x, wa1.y, wa1.z, wa1.w};
#pragma unroll
            for (int i = 0; i < 8; ++i)
#pragma unroll
                for (int j = 0; j < 8; ++j)
                    acc[i][j] += xv[i] * wv[j];
        }
        __syncthreads();
    }

#pragma unroll
    for (int i = 0; i < 8; ++i) {
        int rr = row0 + r0 + i;
        if (rr < N_NODES) {
            ushort4 v0, v1;
            v0.x = f2bf(acc[i][0]); v0.y = f2bf(acc[i][1]);
            v0.z = f2bf(acc[i][2]); v0.w = f2bf(acc[i][3]);
            v1.x = f2bf(acc[i][4]); v1.y = f2bf(acc[i][5]);
            v1.z = f2bf(acc[i][6]); v1.w = f2bf(acc[i][7]);
            *(ushort4*)&Hb[(size_t)rr * EMB + c0]     = v0;
            *(ushort4*)&Hb[(size_t)rr * EMB + c0 + 4] = v1;
        }
    }
}

// ---------------- fused aggregate (v4: batched record preload + 2x gather ILP) ----------------

#define AGG_WAVES 4

__global__ __launch_bounds__(256) void aggregate_kernel(const int* __restrict__ rowptr,
                                                        const unsigned* __restrict__ rec,
                                                        const unsigned* __restrict__ Hb32,
                                                        const float* __restrict__ dinv,
                                                        const float* __restrict__ bias,
                                                        float* __restrict__ out) {
    const int wave = threadIdx.x >> 6;
    const int lane = threadIdx.x & 63;
    const int node = blockIdx.x * AGG_WAVES + wave;
    if (node >= N_NODES) return;

    const int sub = lane >> 4;    // 0..3
    const int dl  = lane & 15;    // 0..15

    const int start = rowptr[node];
    const int end   = rowptr[node + 1];

    float acc[8];
#pragma unroll
    for (int j = 0; j < 8; ++j) acc[j] = 0.0f;

    for (int b = start; b < end; b += 64) {
        int li = b + lane;
        unsigned rl = rec[li < end ? li : end - 1];
        int nb = end - b; if (nb > 64) nb = 64;
        for (int i = 0; i < nb; i += 8) {
            unsigned rA = __shfl(rl, i + sub, 64);
            unsigned rB = __shfl(rl, i + 4 + sub, 64);
            float nA = ((i + sub)     < nb) ? __builtin_bit_cast(float, (rA >> 17) << 16) : 0.0f;
            float nB = ((i + 4 + sub) < nb) ? __builtin_bit_cast(float, (rB >> 17) << 16) : 0.0f;
            int sA = (int)(rA & 0x1FFFFu);
            int sB = (int)(rB & 0x1FFFFu);
            uint4 qA = *(const uint4*)&Hb32[(size_t)sA * 64 + dl * 4];
            uint4 qB = *(const uint4*)&Hb32[(size_t)sB * 64 + dl * 4];
            acc[0] += nA * bflo(qA.x); acc[1] += nA * bfhi(qA.x);
            acc[2] += nA * bflo(qA.y); acc[3] += nA * bfhi(qA.y);
            acc[4] += nA * bflo(qA.z); acc[5] += nA * bfhi(qA.z);
            acc[6] += nA * bflo(qA.w); acc[7] += nA * bfhi(qA.w);
            acc[0] += nB * bflo(qB.x); acc[1] += nB * bfhi(qB.x);
            acc[2] += nB * bflo(qB.y); acc[3] += nB * bfhi(qB.y);
            acc[4] += nB * bflo(qB.z); acc[5] += nB * bfhi(qB.z);
            acc[6] += nB * bflo(qB.w); acc[7] += nB * bfhi(qB.w);
        }
    }

#pragma unroll
    for (int j = 0; j < 8; ++j) {
        acc[j] += __shfl_xor(acc[j], 16, 64);
        acc[j] += __shfl_xor(acc[j], 32, 64);
    }

    if (sub == 0) {
        const float dd = dinv[node];
        const float s2 = dd * dd;
        uint4 q = *(const uint4*)&Hb32[(size_t)node * 64 + dl * 4];
        acc[0] += s2 * bflo(q.x); acc[1] += s2 * bfhi(q.x);
        acc[2] += s2 * bflo(q.y); acc[3] += s2 * bfhi(q.y);
        acc[4] += s2 * bflo(q.z); acc[5] += s2 * bfhi(q.z);
        acc[6] += s2 * bflo(q.w); acc[7] += s2 * bfhi(q.w);

        float4 b0 = *(const float4*)&bias[dl * 8];
        float4 b1 = *(const float4*)&bias[dl * 8 + 4];
        float4 o0 = make_float4(acc[0] + b0.x, acc[1] + b0.y, acc[2] + b0.z, acc[3] + b0.w);
        float4 o1 = make_float4(acc[4] + b1.x, acc[5] + b1.y, acc[6] + b1.z, acc[7] + b1.w);
        *(float4*)&out[(size_t)node * EMB + dl * 8]     = o0;
        *(float4*)&out[(size_t)node * EMB + dl * 8 + 4] = o1;
    }
}

// ---------------- launch ----------------

extern "C" void kernel_launch(void* const* d_in, const int* in_sizes, int n_in,
                              void* d_out, int out_size, void* d_ws, size_t ws_size,
                              hipStream_t stream) {
    const float* x  = (const float*)d_in[0];
    const float* W0 = (const float*)d_in[1];
    const float* b0 = (const float*)d_in[2];
    const float* W1 = (const float*)d_in[3];
    const float* b1 = (const float*)d_in[4];
    const int*   pos = (const int*)d_in[5];
    const int*   neg = (const int*)d_in[6];
    float* out = (float*)d_out;

    // workspace layout (4-byte units)
    float* ws      = (float*)d_ws;
    float* dinv    = ws;                                  // 100000
    unsigned short* hb = (unsigned short*)(ws + 100352);  // [N][128] bf16
    int*   rowptr  = (int*)(ws + 6500352);                // 100001
    int*   bcur    = (int*)(ws + 6600356);                // 256
    int*   wbase   = (int*)(ws + 6600612);                // 256
    unsigned* ptmp = (unsigned*)(ws + 6600872);           // 256*8192 = 2097152
    unsigned* colidx = (unsigned*)(ws + 8698024);         // 1.6M records

    // ---- CSR build (shared by both layers) ----
    binit_kernel<<<1, NWIN, 0, stream>>>(bcur);
    binA_kernel<<<ABLOCKS, 256, 0, stream>>>(pos, neg, bcur, ptmp);
    wscan_kernel<<<1, NWIN, 0, stream>>>(bcur, wbase);
    binC_kernel<<<NWIN, 1024, 0, stream>>>(bcur, wbase, ptmp, rowptr, dinv);
    binB_kernel<<<NWIN, 1024, 0, stream>>>(bcur, rowptr, dinv, ptmp, colidx);

    // ---- layer 0 ----
    gemm_kernel<<<(N_NODES + GTR - 1) / GTR, 256, 0, stream>>>(x, W0, hb);
    aggregate_kernel<<<(N_NODES + AGG_WAVES - 1) / AGG_WAVES, 256, 0, stream>>>(
        rowptr, colidx, (const unsigned*)hb, dinv, b0, out);

    // ---- layer 1 ----
    gemm_kernel<<<(N_NODES + GTR - 1) / GTR, 256, 0, stream>>>(out, W1, hb);
    aggregate_kernel<<<(N_NODES + AGG_WAVES - 1) / AGG_WAVES, 256, 0, stream>>>(
        rowptr, colidx, (const unsigned*)hb, dinv, b1, out);
}

// Round 12
// 245.921 us; speedup vs baseline: 3.0266x; 1.1411x over previous
//
#include <hip/hip_runtime.h>

#define N_NODES 100000
#define EMB 128
#define NE 800000            // edges per edge set (pos / neg)
#define NEDGES (2 * NE)      // total edges

// windowed counting sort for CSR fill
#define NWIN 256
#define WNODES 391           // 256*391 = 100096 >= N_NODES
#define WCAP 8192            // padded per-window capacity (mean 6250, max ~6600)
#define ACHUNK 8192
#define ABLOCKS ((NEDGES + ACHUNK - 1) / ACHUNK)                // 196
#define SEGCAP 7000          // per-window record capacity

typedef __attribute__((ext_vector_type(8))) short bf16x8;
typedef __attribute__((ext_vector_type(4))) float f32x4;

// ---------------- utility ----------------

__device__ __forceinline__ unsigned short f2bf(float f) {
    unsigned u = __builtin_bit_cast(unsigned, f);
    u += 0x7FFFu + ((u >> 16) & 1u);          // round-to-nearest-even
    return (unsigned short)(u >> 16);
}

__device__ __forceinline__ float bflo(unsigned u) { return __builtin_bit_cast(float, u << 16); }
__device__ __forceinline__ float bfhi(unsigned u) { return __builtin_bit_cast(float, u & 0xFFFF0000u); }

__global__ void binit_kernel(int* __restrict__ bcur) {
    int w = threadIdx.x;
    if (w < NWIN) bcur[w] = w * WCAP;
}

// ---- Phase A: bin edges by dst-window into padded regions ----

__global__ __launch_bounds__(256) void binA_kernel(const int* __restrict__ pos,
                                                   const int* __restrict__ neg,
                                                   int* __restrict__ bucket_cursor,
                                                   unsigned* __restrict__ ptmp) {
    __shared__ int lcnt[NWIN];
    __shared__ int lofs[NWIN];
    __shared__ int lcur[NWIN];
    __shared__ int gbase[NWIN];
    __shared__ int stmp[NWIN];
    __shared__ unsigned pbuf[ACHUNK];
    __shared__ unsigned char wbuf[ACHUNK];

    const int tid  = threadIdx.x;
    const int e0   = blockIdx.x * ACHUNK;
    const int ecnt = (NEDGES - e0 < ACHUNK) ? (NEDGES - e0) : ACHUNK;

    if (tid < NWIN) lcnt[tid] = 0;
    __syncthreads();

    for (int k = tid; k < ecnt; k += 256) {
        int i = e0 + k;
        int d = (i < NE) ? pos[NE + i] : neg[i];
        atomicAdd(&lcnt[d / WNODES], 1);
    }
    __syncthreads();

    if (tid < NWIN) stmp[tid] = lcnt[tid];
    __syncthreads();
    for (int off = 1; off < NWIN; off <<= 1) {
        int v = (tid < NWIN && tid >= off) ? stmp[tid - off] : 0;
        __syncthreads();
        if (tid < NWIN) stmp[tid] += v;
        __syncthreads();
    }
    if (tid < NWIN) {
        lofs[tid]  = stmp[tid] - lcnt[tid];
        lcur[tid]  = stmp[tid] - lcnt[tid];
        gbase[tid] = atomicAdd(&bucket_cursor[tid], lcnt[tid]);
    }
    __syncthreads();

    for (int k = tid; k < ecnt; k += 256) {
        int i = e0 + k;
        int s, d;
        if (i < NE) { s = pos[i];      d = pos[NE + i]; }
        else        { s = neg[i - NE]; d = neg[i]; }
        int w = d / WNODES;
        unsigned v = ((unsigned)(d - w * WNODES) << 17) | (unsigned)s;
        int lp = atomicAdd(&lcur[w], 1);
        pbuf[lp] = v;
        wbuf[lp] = (unsigned char)w;
    }
    __syncthreads();

    for (int k = tid; k < ecnt; k += 256) {
        int w = wbuf[k];
        ptmp[gbase[w] + (k - lofs[w])] = pbuf[k];
    }
}

// ---- window-base scan ----

__global__ __launch_bounds__(NWIN) void wscan_kernel(const int* __restrict__ bcur,
                                                     int* __restrict__ wbase) {
    __shared__ int sc[NWIN];
    const int tid = threadIdx.x;
    int t = bcur[tid] - tid * WCAP;
    sc[tid] = t;
    __syncthreads();
    for (int off = 1; off < NWIN; off <<= 1) {
        int v = (tid >= off) ? sc[tid - off] : 0;
        __syncthreads();
        sc[tid] += v;
        __syncthreads();
    }
    wbase[tid] = sc[tid] - t;
}

// ---- Phase C: per-window histogram + scan -> rowptr, dinv ----

__global__ __launch_bounds__(1024) void binC_kernel(const int* __restrict__ bcur,
                                                    const int* __restrict__ wbase,
                                                    const unsigned* __restrict__ ptmp,
                                                    int* __restrict__ rowptr,
                                                    float* __restrict__ dinv) {
    __shared__ int cnt[WNODES];
    __shared__ int sc[512];

    const int w   = blockIdx.x;
    const int lo  = w * WNODES;
    const int hi  = (lo + WNODES < N_NODES) ? lo + WNODES : N_NODES;
    const int nn  = hi - lo;
    const int tot = bcur[w] - w * WCAP;
    const int tid = threadIdx.x;
    const unsigned* __restrict__ rp = ptmp + (size_t)w * WCAP;

    for (int k = tid; k < nn; k += 1024) cnt[k] = 0;
    __syncthreads();

    for (int k = tid; k < tot; k += 1024) {
        atomicAdd(&cnt[rp[k] >> 17], 1);
    }
    __syncthreads();

    if (tid < 512) sc[tid] = (tid < nn) ? cnt[tid] : 0;
    __syncthreads();
    for (int off = 1; off < 512; off <<= 1) {
        int v = (tid < 512 && tid >= off) ? sc[tid - off] : 0;
        __syncthreads();
        if (tid < 512) sc[tid] += v;
        __syncthreads();
    }

    const int b = wbase[w];
    if (tid < nn) {
        rowptr[lo + tid] = b + sc[tid] - cnt[tid];
        dinv[lo + tid]   = rsqrtf((float)cnt[tid] + 1.0f);
    }
    if (w == 0 && tid == 0) rowptr[N_NODES] = NEDGES;
}

// ---- Phase B: per-window sort to CSR order + fuse norm ----

__global__ __launch_bounds__(1024) void binB_kernel(const int* __restrict__ bcur,
                                                    const int* __restrict__ rowptr,
                                                    const float* __restrict__ dinv,
                                                    const unsigned* __restrict__ ptmp,
                                                    unsigned* __restrict__ colidx) {
    __shared__ unsigned colseg[SEGCAP];
    __shared__ int lcur[WNODES];
    __shared__ float dinvw[WNODES];

    const int w    = blockIdx.x;
    const int lo   = w * WNODES;
    const int hi   = (lo + WNODES < N_NODES) ? lo + WNODES : N_NODES;
    const int nn   = hi - lo;
    const int base = rowptr[lo];
    const int tot  = bcur[w] - w * WCAP;
    const int tid  = threadIdx.x;
    const unsigned* __restrict__ rp = ptmp + (size_t)w * WCAP;

    for (int k = tid; k < nn; k += 1024) {
        lcur[k]  = rowptr[lo + k] - base;
        dinvw[k] = dinv[lo + k];
    }
    __syncthreads();

    for (int k = tid; k < tot; k += 1024) {
        unsigned v = rp[k];
        int dl = v >> 17;
        int s  = (int)(v & 0x1FFFFu);
        float nrm = dinv[s] * dinvw[dl];
        unsigned u = __builtin_bit_cast(unsigned, nrm);
        unsigned nb = (u + 0x7FFFu + ((u >> 16) & 1u)) >> 16;
        int lp = atomicAdd(&lcur[dl], 1);
        if (lp < SEGCAP) colseg[lp] = (nb << 17) | (unsigned)s;
    }
    __syncthreads();

    for (int k = tid; k < tot; k += 1024) colidx[base + k] = colseg[k];
}

// ---------------- GEMM v4 (MFMA bf16): Hb[N][128] = bf16(X @ W) ----------------
// 64 rows/block = 4 waves x 16 rows. W converted once/block to LDS, pre-swizzled
// into B-fragment order: Wb[((ct*4+ks)*64+lane)*8 + j] = bf16(W[ks*32+(lane>>4)*8+j][ct*16+(lane&15)]).
// A frag: lane = row(l&15) + 16*kgroup(l>>4), 8 contiguous k per lane.
// C/D: col = lane&15, row = (lane>>4)*4 + reg  [m89-verified].

#define GROWS 64

__global__ __launch_bounds__(256) void gemm_kernel(const float* __restrict__ X,
                                                   const float* __restrict__ W,
                                                   unsigned short* __restrict__ Hb) {
    __shared__ unsigned short Wb[128 * 128];   // 32 KB

    const int tid  = threadIdx.x;
    const int row0 = blockIdx.x * GROWS;

    // stage W: coalesced float4 reads, swizzled bf16 LDS writes
    for (int i = tid * 4; i < 128 * 128; i += 256 * 4) {
        float4 v = *(const float4*)&W[i];
        int k = i >> 7;
        int c = i & 127;
        int ks = k >> 5;
        int kg = (k >> 3) & 3;
        int j  = k & 7;
        float vv[4] = {v.x, v.y, v.z, v.w};
#pragma unroll
        for (int q = 0; q < 4; ++q) {
            int cc   = c + q;
            int ct   = cc >> 4;
            int lane = (cc & 15) + 16 * kg;
            Wb[((ct * 4 + ks) * 64 + lane) * 8 + j] = f2bf(vv[q]);
        }
    }
    __syncthreads();

    const int wave = tid >> 6;
    const int lane = tid & 63;
    const int r    = lane & 15;
    const int kg   = lane >> 4;

    int row = row0 + wave * 16 + r;
    int rowc = (row < N_NODES) ? row : N_NODES - 1;   // clamped for loads

    // A fragments: 4 k-steps, 8 contiguous k each
    bf16x8 a[4];
#pragma unroll
    for (int ks = 0; ks < 4; ++ks) {
        const float4* p = (const float4*)&X[(size_t)rowc * EMB + ks * 32 + kg * 8];
        float4 u = p[0];
        float4 v = p[1];
        bf16x8 av;
        av[0] = (short)f2bf(u.x); av[1] = (short)f2bf(u.y);
        av[2] = (short)f2bf(u.z); av[3] = (short)f2bf(u.w);
        av[4] = (short)f2bf(v.x); av[5] = (short)f2bf(v.y);
        av[6] = (short)f2bf(v.z); av[7] = (short)f2bf(v.w);
        a[ks] = av;
    }

    f32x4 acc[8];
#pragma unroll
    for (int ct = 0; ct < 8; ++ct) acc[ct] = (f32x4){0.f, 0.f, 0.f, 0.f};

#pragma unroll
    for (int ct = 0; ct < 8; ++ct) {
#pragma unroll
        for (int ks = 0; ks < 4; ++ks) {
            bf16x8 b = *(bf16x8*)&Wb[((ct * 4 + ks) * 64 + lane) * 8];
            acc[ct] = __builtin_amdgcn_mfma_f32_16x16x32_bf16(a[ks], b, acc[ct], 0, 0, 0);
        }
    }

    // write out: lane holds col=lane&15, rows (lane>>4)*4 + 0..3 of each col-tile
    const int orow0 = row0 + wave * 16 + (lane >> 4) * 4;
    const int oc    = lane & 15;
#pragma unroll
    for (int reg = 0; reg < 4; ++reg) {
        int orow = orow0 + reg;
        if (orow < N_NODES) {
#pragma unroll
            for (int ct = 0; ct < 8; ++ct) {
                Hb[(size_t)orow * EMB + ct * 16 + oc] = f2bf(acc[ct][reg]);
            }
        }
    }
}

// ---------------- fused aggregate v5: 4-deep gather ILP ----------------
// wave = one node; preload 64 records into lane regs; 16 edges/iter in 4
// groups of 4 (sub = lane>>4), dl = lane&15 covers dims [dl*8, dl*8+8).

#define AGG_WAVES 4

__global__ __launch_bounds__(256) void aggregate_kernel(const int* __restrict__ rowptr,
                                                        const unsigned* __restrict__ rec,
                                                        const unsigned* __restrict__ Hb32,
                                                        const float* __restrict__ dinv,
                                                        const float* __restrict__ bias,
                                                        float* __restrict__ out) {
    const int wave = threadIdx.x >> 6;
    const int lane = threadIdx.x & 63;
    const int node = blockIdx.x * AGG_WAVES + wave;
    if (node >= N_NODES) return;

    const int sub = lane >> 4;    // 0..3
    const int dl  = lane & 15;    // 0..15

    const int start = rowptr[node];
    const int end   = rowptr[node + 1];

    float acc[8];
#pragma unroll
    for (int j = 0; j < 8; ++j) acc[j] = 0.0f;

    for (int b = start; b < end; b += 64) {
        int li = b + lane;
        unsigned rl = rec[li < end ? li : end - 1];
        int nb = end - b; if (nb > 64) nb = 64;
        for (int i = 0; i < nb; i += 16) {
            unsigned rA = __shfl(rl, i + sub,      64);
            unsigned rB = __shfl(rl, i + 4 + sub,  64);
            unsigned rC = __shfl(rl, i + 8 + sub,  64);
            unsigned rD = __shfl(rl, i + 12 + sub, 64);
            float nA = ((i + sub)      < nb) ? __builtin_bit_cast(float, (rA >> 17) << 16) : 0.0f;
            float nB = ((i + 4 + sub)  < nb) ? __builtin_bit_cast(float, (rB >> 17) << 16) : 0.0f;
            float nC = ((i + 8 + sub)  < nb) ? __builtin_bit_cast(float, (rC >> 17) << 16) : 0.0f;
            float nD = ((i + 12 + sub) < nb) ? __builtin_bit_cast(float, (rD >> 17) << 16) : 0.0f;
            int sA = (int)(rA & 0x1FFFFu);
            int sB = (int)(rB & 0x1FFFFu);
            int sC = (int)(rC & 0x1FFFFu);
            int sD = (int)(rD & 0x1FFFFu);
            uint4 qA = *(const uint4*)&Hb32[(size_t)sA * 64 + dl * 4];
            uint4 qB = *(const uint4*)&Hb32[(size_t)sB * 64 + dl * 4];
            uint4 qC = *(const uint4*)&Hb32[(size_t)sC * 64 + dl * 4];
            uint4 qD = *(const uint4*)&Hb32[(size_t)sD * 64 + dl * 4];
            acc[0] += nA * bflo(qA.x); acc[1] += nA * bfhi(qA.x);
            acc[2] += nA * bflo(qA.y); acc[3] += nA * bfhi(qA.y);
            acc[4] += nA * bflo(qA.z); acc[5] += nA * bfhi(qA.z);
            acc[6] += nA * bflo(qA.w); acc[7] += nA * bfhi(qA.w);
            acc[0] += nB * bflo(qB.x); acc[1] += nB * bfhi(qB.x);
            acc[2] += nB * bflo(qB.y); acc[3] += nB * bfhi(qB.y);
            acc[4] += nB * bflo(qB.z); acc[5] += nB * bfhi(qB.z);
            acc[6] += nB * bflo(qB.w); acc[7] += nB * bfhi(qB.w);
            acc[0] += nC * bflo(qC.x); acc[1] += nC * bfhi(qC.x);
            acc[2] += nC * bflo(qC.y); acc[3] += nC * bfhi(qC.y);
            acc[4] += nC * bflo(qC.z); acc[5] += nC * bfhi(qC.z);
            acc[6] += nC * bflo(qC.w); acc[7] += nC * bfhi(qC.w);
            acc[0] += nD * bflo(qD.x); acc[1] += nD * bfhi(qD.x);
            acc[2] += nD * bflo(qD.y); acc[3] += nD * bfhi(qD.y);
            acc[4] += nD * bflo(qD.z); acc[5] += nD * bfhi(qD.z);
            acc[6] += nD * bflo(qD.w); acc[7] += nD * bfhi(qD.w);
        }
    }

#pragma unroll
    for (int j = 0; j < 8; ++j) {
        acc[j] += __shfl_xor(acc[j], 16, 64);
        acc[j] += __shfl_xor(acc[j], 32, 64);
    }

    if (sub == 0) {
        const float dd = dinv[node];
        const float s2 = dd * dd;
        uint4 q = *(const uint4*)&Hb32[(size_t)node * 64 + dl * 4];
        acc[0] += s2 * bflo(q.x); acc[1] += s2 * bfhi(q.x);
        acc[2] += s2 * bflo(q.y); acc[3] += s2 * bfhi(q.y);
        acc[4] += s2 * bflo(q.z); acc[5] += s2 * bfhi(q.z);
        acc[6] += s2 * bflo(q.w); acc[7] += s2 * bfhi(q.w);

        float4 b0 = *(const float4*)&bias[dl * 8];
        float4 b1 = *(const float4*)&bias[dl * 8 + 4];
        float4 o0 = make_float4(acc[0] + b0.x, acc[1] + b0.y, acc[2] + b0.z, acc[3] + b0.w);
        float4 o1 = make_float4(acc[4] + b1.x, acc[5] + b1.y, acc[6] + b1.z, acc[7] + b1.w);
        *(float4*)&out[(size_t)node * EMB + dl * 8]     = o0;
        *(float4*)&out[(size_t)node * EMB + dl * 8 + 4] = o1;
    }
}

// ---------------- launch ----------------

extern "C" void kernel_launch(void* const* d_in, const int* in_sizes, int n_in,
                              void* d_out, int out_size, void* d_ws, size_t ws_size,
                              hipStream_t stream) {
    const float* x  = (const float*)d_in[0];
    const float* W0 = (const float*)d_in[1];
    const float* b0 = (const float*)d_in[2];
    const float* W1 = (const float*)d_in[3];
    const float* b1 = (const float*)d_in[4];
    const int*   pos = (const int*)d_in[5];
    const int*   neg = (const int*)d_in[6];
    float* out = (float*)d_out;

    // workspace layout (4-byte units)
    float* ws      = (float*)d_ws;
    float* dinv    = ws;                                  // 100000
    unsigned short* hb = (unsigned short*)(ws + 100352);  // [N][128] bf16
    int*   rowptr  = (int*)(ws + 6500352);                // 100001
    int*   bcur    = (int*)(ws + 6600356);                // 256
    int*   wbase   = (int*)(ws + 6600612);                // 256
    unsigned* ptmp = (unsigned*)(ws + 6600872);           // 256*8192
    unsigned* colidx = (unsigned*)(ws + 8698024);         // 1.6M records

    // ---- CSR build (shared by both layers) ----
    binit_kernel<<<1, NWIN, 0, stream>>>(bcur);
    binA_kernel<<<ABLOCKS, 256, 0, stream>>>(pos, neg, bcur, ptmp);
    wscan_kernel<<<1, NWIN, 0, stream>>>(bcur, wbase);
    binC_kernel<<<NWIN, 1024, 0, stream>>>(bcur, wbase, ptmp, rowptr, dinv);
    binB_kernel<<<NWIN, 1024, 0, stream>>>(bcur, rowptr, dinv, ptmp, colidx);

    // ---- layer 0 ----
    gemm_kernel<<<(N_NODES + GROWS - 1) / GROWS, 256, 0, stream>>>(x, W0, hb);
    aggregate_kernel<<<(N_NODES + AGG_WAVES - 1) / AGG_WAVES, 256, 0, stream>>>(
        rowptr, colidx, (const unsigned*)hb, dinv, b0, out);

    // ---- layer 1 ----
    gemm_kernel<<<(N_NODES + GROWS - 1) / GROWS, 256, 0, stream>>>(out, W1, hb);
    aggregate_kernel<<<(N_NODES + AGG_WAVES - 1) / AGG_WAVES, 256, 0, stream>>>(
        rowptr, colidx, (const unsigned*)hb, dinv, b1, out);
}